// Round 3
// baseline (660.175 us; speedup 1.0000x reference)
//
#include <hip/hip_runtime.h>
#include <hip/hip_cooperative_groups.h>
#include <math.h>

namespace cg = cooperative_groups;

#define H 18
#define NS 65536
#define AD 4
#define ITERS 6
#define DELTA 16.0f
#define GCAP 8192
#define SCAP 2048
#define NWG 256
#define WGS 256

__device__ __forceinline__ unsigned encf(float f) {
    unsigned u = __float_as_uint(f);
    return (u & 0x80000000u) ? ~u : (u | 0x80000000u);
}
__device__ __forceinline__ float decf(unsigned u) {
    return __uint_as_float((u & 0x80000000u) ? (u & 0x7FFFFFFFu) : ~u);
}
__device__ __forceinline__ float clamp4(float x) {
    return fminf(fmaxf(x, -4.0f), 4.0f);
}

// wave-aggregated push of (val, idx) into global list if val >= thr
__device__ __forceinline__ void push_cand(float val, unsigned idx, float thr,
                                          unsigned* __restrict__ cnt,
                                          float* __restrict__ listv,
                                          unsigned* __restrict__ listi) {
    bool pred = val >= thr;
    unsigned long long mb = __ballot(pred);
    int lane = threadIdx.x & 63;
    int c = __popcll(mb);
    unsigned base = 0;
    if (lane == 0 && c) base = atomicAdd(cnt, (unsigned)c);
    base = __shfl(base, 0);
    if (pred) {
        unsigned p = base + (unsigned)__popcll(mb & ((1ull << lane) - 1ull));
        if (p < GCAP) { listv[p] = val; listi[p] = idx; }
    }
}

__global__ void __launch_bounds__(WGS) k_mppi(
        const float* __restrict__ pi, const float* __restrict__ noise,
        const float* __restrict__ target, float* __restrict__ out,
        float* __restrict__ meanbuf, unsigned* __restrict__ slots,
        unsigned* __restrict__ cnts, float* __restrict__ listv,
        unsigned* __restrict__ listi) {
    cg::grid_group grid = cg::this_grid();
    __shared__ float tgt[H * AD];
    __shared__ float mnL[H * AD];
    __shared__ float wm[4];
    __shared__ float s_bthr, s_bpimax, s_S;
    __shared__ unsigned s_fcnt;
    __shared__ float lv[SCAP];
    __shared__ unsigned li[SCAP];
    __shared__ float buf[64 * 73];
    __shared__ float w[64];

    const int tid = threadIdx.x;
    const int wg = blockIdx.x;
    const int n = wg * WGS + tid;
    const int lane = tid & 63;

    if (tid < H * AD) tgt[tid] = target[tid];
    if (wg == 0) {
        if (tid < ITERS) { slots[tid] = 0u; cnts[tid] = 0u; }
        if (tid >= 128 && tid < 128 + H * AD) {
            int t = tid - 128;
            meanbuf[t] = pi[(size_t)(t >> 2) * NS * AD + (t & 3)];  // pi[:,0,:]
        }
    }
    __syncthreads();

    // ---- pi candidate value (iteration-invariant, stays in a register)
    const float4* pi4 = (const float4*)pi;
    float acc = 0.0f;
#pragma unroll
    for (int h = 0; h < H; ++h) {
        float4 p = pi4[(size_t)h * NS + n];
        float c;
        c = p.x - tgt[h * 4 + 0]; acc += c * c;
        c = p.y - tgt[h * 4 + 1]; acc += c * c;
        c = p.z - tgt[h * 4 + 2]; acc += c * c;
        c = p.w - tgt[h * 4 + 3]; acc += c * c;
    }
    const float vpi = -acc;
    {
        float m = vpi;
        for (int off = 32; off; off >>= 1) m = fmaxf(m, __shfl_xor(m, off));
        if (lane == 0) wm[tid >> 6] = m;
    }
    __syncthreads();
    if (tid == 0) s_bpimax = fmaxf(fmaxf(wm[0], wm[1]), fmaxf(wm[2], wm[3]));

    // ---- prefetch iter-0 noise into registers
    const float4* nz4 = (const float4*)noise;
    float4 nz[H];
#pragma unroll
    for (int h = 0; h < H; ++h) nz[h] = nz4[(size_t)h * NS + n];

    grid.sync();  // init (meanbuf/slots/cnts) visible everywhere

    float scale = 0.5f;  // iter 0: STD*std = 0.5*1; iters>=1: 0.5*2 = 1.0
    for (int i = 0; i < ITERS; ++i) {
        // ---- phase A: cem value from registers, block max, push candidates
        if (tid < H * AD) mnL[tid] = meanbuf[tid];
        __syncthreads();
        float a2 = 0.0f;
#pragma unroll
        for (int h = 0; h < H; ++h) {
            float c;
            c = clamp4(mnL[h * 4 + 0] + scale * nz[h].x) - tgt[h * 4 + 0]; a2 += c * c;
            c = clamp4(mnL[h * 4 + 1] + scale * nz[h].y) - tgt[h * 4 + 1]; a2 += c * c;
            c = clamp4(mnL[h * 4 + 2] + scale * nz[h].z) - tgt[h * 4 + 2]; a2 += c * c;
            c = clamp4(mnL[h * 4 + 3] + scale * nz[h].w) - tgt[h * 4 + 3]; a2 += c * c;
        }
        const float vc = -a2;
        {
            float m = vc;
            for (int off = 32; off; off >>= 1) m = fmaxf(m, __shfl_xor(m, off));
            if (lane == 0) wm[tid >> 6] = m;
        }
        __syncthreads();
        if (tid == 0) {
            float bt = fmaxf(fmaxf(fmaxf(wm[0], wm[1]), fmaxf(wm[2], wm[3])), s_bpimax);
            s_bthr = bt;
            atomicMax(&slots[i], encf(bt));
        }
        __syncthreads();
        const float pthr = s_bthr - DELTA;  // conservative vs global threshold
        push_cand(vpi, (unsigned)n, pthr, &cnts[i], listv, listi);
        push_cand(vc, (unsigned)(NS + n), pthr, &cnts[i], listv, listi);

        grid.sync();  // A: slots[i] + candidate list complete

        // ---- prefetch next iter's noise; drains at sync B, overlapping wg0
        if (i + 1 < ITERS) {
            const float4* nzn = nz4 + (size_t)(i + 1) * H * NS;
#pragma unroll
            for (int h = 0; h < H; ++h) nz[h] = nzn[(size_t)h * NS + n];
        }

        // ---- phase B (wg0 only): filter by true global max, exact top-64,
        //      softmax, elite gather, momentum mean update
        if (wg == 0) {
            const float gmax = decf(slots[i]);
            const float thr = gmax - DELTA;
            if (tid == 0) s_fcnt = 0u;
            __syncthreads();
            unsigned cnt = cnts[i]; if (cnt > GCAP) cnt = GCAP;
            for (unsigned k = tid; k < cnt; k += WGS) {
                float val = listv[k];
                if (val >= thr) {
                    unsigned p = atomicAdd(&s_fcnt, 1u);
                    if (p < SCAP) { lv[p] = val; li[p] = listi[k]; }
                }
            }
            __syncthreads();
            unsigned fc = s_fcnt; if (fc > SCAP) fc = SCAP;
            unsigned P2 = 64; while (P2 < fc) P2 <<= 1;
            for (unsigned k = fc + tid; k < P2; k += WGS) { lv[k] = -INFINITY; li[k] = 0x7FFFFFFFu; }
            __syncthreads();
            for (unsigned kk = 2; kk <= P2; kk <<= 1) {
                for (unsigned j = kk >> 1; j > 0; j >>= 1) {
                    for (unsigned x = tid; x < P2; x += WGS) {
                        unsigned l = x ^ j;
                        if (l > x) {
                            float v0 = lv[x], v1 = lv[l];
                            unsigned i0 = li[x], i1 = li[l];
                            bool gt = (v0 > v1) || (v0 == v1 && i0 < i1);
                            bool desc = ((x & kk) == 0);
                            if (desc ? !gt : gt) { lv[x] = v1; lv[l] = v0; li[x] = i1; li[l] = i0; }
                        }
                    }
                    __syncthreads();
                }
            }
            int E = (fc < 64u) ? (int)fc : 64;
            if (tid < 64) {
                float we = (tid < E) ? expf(lv[tid] - lv[0]) : 0.0f;
                w[tid] = we;
                float s = we;
                for (int off = 32; off; off >>= 1) s += __shfl_xor(s, off);
                if (tid == 0) s_S = s;
            }
            __syncthreads();
            const float invS = 1.0f / (s_S * (1.0f + 1e-9f));
            {
                int e = tid >> 2, aa = tid & 3;
                float av[H];
                unsigned idx = (e < E) ? li[e] : 0u;
                if (e < E) {
                    if (idx < NS) {
#pragma unroll
                        for (int h = 0; h < H; ++h)
                            av[h] = pi[(size_t)h * NS * AD + (size_t)idx * AD + aa];
                    } else {
                        unsigned mm = idx - NS;
                        const float* nzi = noise + (size_t)i * H * NS * AD;
#pragma unroll
                        for (int h = 0; h < H; ++h)
                            av[h] = nzi[(size_t)h * NS * AD + (size_t)mm * AD + aa];
#pragma unroll
                        for (int h = 0; h < H; ++h)
                            av[h] = clamp4(mnL[h * 4 + aa] + scale * av[h]);
                    }
                } else {
#pragma unroll
                    for (int h = 0; h < H; ++h) av[h] = 0.0f;
                }
                if (i == ITERS - 1 && e == 0) {
#pragma unroll
                    for (int h = 0; h < H; ++h) out[h * 4 + aa] = av[h];
                }
                float we = (e < E) ? w[e] : 0.0f;
#pragma unroll
                for (int h = 0; h < H; ++h) buf[e * 73 + h * 4 + aa] = we * av[h];
            }
            __syncthreads();
            if (tid < H * AD) {
                float s = 0.0f;
#pragma unroll 8
                for (int e = 0; e < 64; ++e) s += buf[e * 73 + tid];
                meanbuf[tid] = 0.1f * mnL[tid] + 0.9f * (s * invS);
            }
        }

        grid.sync();  // B: updated mean visible
        scale = 1.0f;
    }
}

extern "C" void kernel_launch(void* const* d_in, const int* in_sizes, int n_in,
                              void* d_out, int out_size, void* d_ws, size_t ws_size,
                              hipStream_t stream) {
    const float* pi     = (const float*)d_in[0];
    const float* noise  = (const float*)d_in[1];
    const float* target = (const float*)d_in[2];
    float* out = (float*)d_out;

    float* ws = (float*)d_ws;
    float* meanbuf   = ws;                              // 128 floats
    unsigned* slots  = (unsigned*)(ws + 128);           // 8
    unsigned* cnts   = slots + 8;                       // 8
    float* listv     = (float*)(cnts + 8);              // GCAP
    unsigned* listi  = (unsigned*)(listv + GCAP);       // GCAP

    void* args[] = {(void*)&pi, (void*)&noise, (void*)&target, (void*)&out,
                    (void*)&meanbuf, (void*)&slots, (void*)&cnts,
                    (void*)&listv, (void*)&listi};
    hipLaunchCooperativeKernel((void*)k_mppi, dim3(NWG), dim3(WGS), args, 0, stream);
}

// Round 4
// 210.688 us; speedup vs baseline: 3.1334x; 3.1334x over previous
//
#include <hip/hip_runtime.h>
#include <math.h>

#define H 18
#define NS 65536
#define AD 4
#define ITERS 6
#define DELTA 16.0f
#define GCAP 16384
#define SCAP 2048
#define NWG 256
#define WGS 256

__device__ __forceinline__ unsigned encf(float f) {
    unsigned u = __float_as_uint(f);
    return (u & 0x80000000u) ? ~u : (u | 0x80000000u);
}
__device__ __forceinline__ float decf(unsigned u) {
    return __uint_as_float((u & 0x80000000u) ? (u & 0x7FFFFFFFu) : ~u);
}
__device__ __forceinline__ float clamp4(float x) {
    return fminf(fmaxf(x, -4.0f), 4.0f);
}

// ctrl layout: [0]=pimax slot, [1]=pilist count, [2..7]=per-iter max slots,
//              [8..13]=per-iter list counts
__global__ void k_zero(unsigned* __restrict__ ctrl) {
    if (threadIdx.x < 16) ctrl[threadIdx.x] = 0u;
}

__device__ __forceinline__ void push_cand(float val, unsigned idx, float thr,
                                          unsigned* __restrict__ cnt,
                                          float* __restrict__ listv,
                                          unsigned* __restrict__ listi) {
    bool pred = val >= thr;
    unsigned long long mb = __ballot(pred);
    int lane = threadIdx.x & 63;
    int c = __popcll(mb);
    unsigned base = 0;
    if (lane == 0 && c) base = atomicAdd(cnt, (unsigned)c);
    base = __shfl(base, 0);
    if (pred) {
        unsigned p = base + (unsigned)__popcll(mb & ((1ull << lane) - 1ull));
        if (p < GCAP) { listv[p] = val; listi[p] = idx; }
    }
}

__global__ void __launch_bounds__(WGS) k_step(
        const float* __restrict__ pi, const float* __restrict__ noise,
        const float* __restrict__ target, unsigned* __restrict__ ctrl,
        float* __restrict__ meanarr, float* __restrict__ plv,
        unsigned* __restrict__ pli, float* __restrict__ lvb,
        unsigned* __restrict__ lib, int iter) {
    __shared__ float tgt[H * AD], mnL[H * AD];
    __shared__ float wmc[4], wmp[4];
    __shared__ float flv[SCAP];
    __shared__ unsigned fli[SCAP];
    __shared__ float buf[64 * 73];
    __shared__ float w[64];
    __shared__ unsigned s_fcnt;
    __shared__ float s_S, s_thr, s_thr_pi;

    const int tid = threadIdx.x;
    const int n = blockIdx.x * WGS + tid;
    const int lane = tid & 63;

    if (tid < H * AD) tgt[tid] = target[tid];
    if (tid == 0) s_fcnt = 0u;

    // prefetch this iter's noise slice into registers (consumed in phase A)
    const float4* nz4 = (const float4*)noise + (size_t)iter * H * NS;
    float4 nz[H];
#pragma unroll
    for (int h = 0; h < H; ++h) nz[h] = nz4[(size_t)h * NS + n];

    float vpi = 0.0f;
    if (iter == 0) {
        const float4* pi4 = (const float4*)pi;
        __syncthreads();  // tgt ready
        float acc = 0.0f;
#pragma unroll
        for (int h = 0; h < H; ++h) {
            float4 p = pi4[(size_t)h * NS + n];
            float c;
            c = p.x - tgt[h * 4 + 0]; acc += c * c;
            c = p.y - tgt[h * 4 + 1]; acc += c * c;
            c = p.z - tgt[h * 4 + 2]; acc += c * c;
            c = p.w - tgt[h * 4 + 3]; acc += c * c;
        }
        vpi = -acc;
        if (tid < H * AD) {
            float m0 = pi[(size_t)(tid >> 2) * NS * AD + (tid & 3)];  // pi[:,0,:]
            mnL[tid] = m0;
            meanarr[tid] = m0;
        }
        __syncthreads();
    } else {
        // ---- phase B for iter-1 (redundant per block; all blocks identical)
        if (tid < H * AD) mnL[tid] = meanarr[(size_t)(iter - 1) * H * AD + tid];
        __syncthreads();  // tgt + mnL + s_fcnt ready
        const float gmax = decf(ctrl[2 + (iter - 1)]);
        const float thr = gmax - DELTA;
        const float pscale = (iter == 1) ? 0.5f : 1.0f;
        unsigned pcnt = ctrl[1];              if (pcnt > GCAP) pcnt = GCAP;
        unsigned ccnt = ctrl[8 + (iter - 1)]; if (ccnt > GCAP) ccnt = GCAP;
        const float* lvp = lvb + (size_t)(iter - 1) * GCAP;
        const unsigned* lip = lib + (size_t)(iter - 1) * GCAP;
        for (unsigned k = tid; k < pcnt; k += WGS) {
            float val = plv[k];
            if (val >= thr) {
                unsigned p = atomicAdd(&s_fcnt, 1u);
                if (p < SCAP) { flv[p] = val; fli[p] = pli[k]; }
            }
        }
        for (unsigned k = tid; k < ccnt; k += WGS) {
            float val = lvp[k];
            if (val >= thr) {
                unsigned p = atomicAdd(&s_fcnt, 1u);
                if (p < SCAP) { flv[p] = val; fli[p] = lip[k]; }
            }
        }
        __syncthreads();
        unsigned fc = s_fcnt; if (fc > SCAP) fc = SCAP;
        if (fc > 64u) {  // rare: exact top-64 needed, bitonic sort
            unsigned P2 = 64; while (P2 < fc) P2 <<= 1;
            for (unsigned k = fc + tid; k < P2; k += WGS) { flv[k] = -INFINITY; fli[k] = 0x7FFFFFFFu; }
            __syncthreads();
            for (unsigned kk = 2; kk <= P2; kk <<= 1) {
                for (unsigned j = kk >> 1; j; j >>= 1) {
                    for (unsigned x = tid; x < P2; x += WGS) {
                        unsigned l = x ^ j;
                        if (l > x) {
                            float v0 = flv[x], v1 = flv[l];
                            unsigned i0 = fli[x], i1 = fli[l];
                            bool gt = (v0 > v1) || (v0 == v1 && i0 < i1);
                            bool desc = ((x & kk) == 0);
                            if (desc ? !gt : gt) { flv[x] = v1; flv[l] = v0; fli[x] = i1; fli[l] = i0; }
                        }
                    }
                    __syncthreads();
                }
            }
        }
        const int E = (fc < 64u) ? (int)fc : 64;
        if (tid < 64) {
            float we = (tid < E) ? expf(flv[tid] - gmax) : 0.0f;  // max == gmax
            w[tid] = we;
            float s = we;
            for (int off = 32; off; off >>= 1) s += __shfl_xor(s, off);
            if (tid == 0) s_S = s;
        }
        __syncthreads();
        const float invS = 1.0f / (s_S + 1e-9f);
        {
            const int e = tid >> 2, aa = tid & 3;
            float av[H];
            unsigned idx = (e < E) ? fli[e] : 0u;
            if (e < E) {
                if (idx < NS) {
#pragma unroll
                    for (int h = 0; h < H; ++h)
                        av[h] = pi[(size_t)h * NS * AD + (size_t)idx * AD + aa];
                } else {
                    const unsigned mm = idx - NS;
                    const float* nzi = noise + (size_t)(iter - 1) * H * NS * AD;
#pragma unroll
                    for (int h = 0; h < H; ++h)
                        av[h] = clamp4(mnL[h * 4 + aa] + pscale * nzi[(size_t)h * NS * AD + (size_t)mm * AD + aa]);
                }
            } else {
#pragma unroll
                for (int h = 0; h < H; ++h) av[h] = 0.0f;
            }
            const float we = (e < E) ? w[e] : 0.0f;
#pragma unroll
            for (int h = 0; h < H; ++h) buf[e * 73 + h * 4 + aa] = we * av[h];
        }
        __syncthreads();
        if (tid < H * AD) {
            float s = 0.0f;
#pragma unroll 8
            for (int e = 0; e < 64; ++e) s += buf[e * 73 + tid];
            float nm = 0.1f * mnL[tid] + 0.9f * (s * invS);
            mnL[tid] = nm;
            meanarr[(size_t)iter * H * AD + tid] = nm;
        }
        __syncthreads();
    }

    // ---- phase A: cem values for this iter from prefetched registers
    const float scale = (iter == 0) ? 0.5f : 1.0f;
    float a2 = 0.0f;
#pragma unroll
    for (int h = 0; h < H; ++h) {
        float c;
        c = clamp4(mnL[h * 4 + 0] + scale * nz[h].x) - tgt[h * 4 + 0]; a2 += c * c;
        c = clamp4(mnL[h * 4 + 1] + scale * nz[h].y) - tgt[h * 4 + 1]; a2 += c * c;
        c = clamp4(mnL[h * 4 + 2] + scale * nz[h].z) - tgt[h * 4 + 2]; a2 += c * c;
        c = clamp4(mnL[h * 4 + 3] + scale * nz[h].w) - tgt[h * 4 + 3]; a2 += c * c;
    }
    const float vc = -a2;

    float mc = vc;
    for (int off = 32; off; off >>= 1) mc = fmaxf(mc, __shfl_xor(mc, off));
    if (lane == 0) wmc[tid >> 6] = mc;
    if (iter == 0) {
        float mp = vpi;
        for (int off = 32; off; off >>= 1) mp = fmaxf(mp, __shfl_xor(mp, off));
        if (lane == 0) wmp[tid >> 6] = mp;
    }
    __syncthreads();
    if (tid == 0) {
        float bmc = fmaxf(fmaxf(wmc[0], wmc[1]), fmaxf(wmc[2], wmc[3]));
        if (iter == 0) {
            float bmp = fmaxf(fmaxf(wmp[0], wmp[1]), fmaxf(wmp[2], wmp[3]));
            unsigned ep = encf(bmp);
            unsigned op = atomicMax(&ctrl[0], ep);
            s_thr_pi = decf(op > ep ? op : ep) - DELTA;   // watermark <= pimax
            float ba = fmaxf(bmc, bmp);
            unsigned ea = encf(ba);
            unsigned oa = atomicMax(&ctrl[2], ea);
            s_thr = decf(oa > ea ? oa : ea) - DELTA;
        } else {
            float ba = fmaxf(bmc, decf(ctrl[0]));  // fold final pimax
            unsigned ea = encf(ba);
            unsigned oa = atomicMax(&ctrl[2 + iter], ea);
            s_thr = decf(oa > ea ? oa : ea) - DELTA;
        }
    }
    __syncthreads();
    if (iter == 0) push_cand(vpi, (unsigned)n, s_thr_pi, &ctrl[1], plv, pli);
    push_cand(vc, (unsigned)(NS + n), s_thr, &ctrl[8 + iter],
              lvb + (size_t)iter * GCAP, lib + (size_t)iter * GCAP);
}

// ---- final: exact argmax over pilist U list5, gather its actions, write out
__global__ void __launch_bounds__(256) k_fin(
        const float* __restrict__ pi, const float* __restrict__ noise,
        const unsigned* __restrict__ ctrl, const float* __restrict__ meanarr,
        const float* __restrict__ plv, const unsigned* __restrict__ pli,
        const float* __restrict__ lv5, const unsigned* __restrict__ li5,
        float* __restrict__ out) {
    __shared__ float mnL[H * AD];
    __shared__ float bv[4];
    __shared__ unsigned bi[4];
    int tid = threadIdx.x, lane = tid & 63;
    if (tid < H * AD) mnL[tid] = meanarr[(size_t)5 * H * AD + tid];
    unsigned pcnt = ctrl[1];  if (pcnt > GCAP) pcnt = GCAP;
    unsigned c5   = ctrl[13]; if (c5 > GCAP) c5 = GCAP;
    float best = -INFINITY; unsigned bidx = 0xFFFFFFFFu;
    for (unsigned k = tid; k < pcnt; k += 256) {
        float v = plv[k]; unsigned ix = pli[k];
        if (v > best || (v == best && ix < bidx)) { best = v; bidx = ix; }
    }
    for (unsigned k = tid; k < c5; k += 256) {
        float v = lv5[k]; unsigned ix = li5[k];
        if (v > best || (v == best && ix < bidx)) { best = v; bidx = ix; }
    }
    for (int off = 32; off; off >>= 1) {
        float ov = __shfl_xor(best, off);
        unsigned oi = __shfl_xor(bidx, off);
        if (ov > best || (ov == best && oi < bidx)) { best = ov; bidx = oi; }
    }
    if (lane == 0) { bv[tid >> 6] = best; bi[tid >> 6] = bidx; }
    __syncthreads();
    if (tid == 0) {
        for (int q = 1; q < 4; ++q)
            if (bv[q] > bv[0] || (bv[q] == bv[0] && bi[q] < bi[0])) { bv[0] = bv[q]; bi[0] = bi[q]; }
    }
    __syncthreads();
    unsigned idx = bi[0];
    if (tid < H * AD) {
        int h = tid >> 2, a = tid & 3;
        float o;
        if (idx < NS) o = pi[(size_t)h * NS * AD + (size_t)idx * AD + a];
        else o = clamp4(mnL[tid] + noise[(size_t)5 * H * NS * AD + (size_t)h * NS * AD + (size_t)(idx - NS) * AD + a]);
        out[tid] = o;
    }
}

extern "C" void kernel_launch(void* const* d_in, const int* in_sizes, int n_in,
                              void* d_out, int out_size, void* d_ws, size_t ws_size,
                              hipStream_t stream) {
    const float* pi     = (const float*)d_in[0];
    const float* noise  = (const float*)d_in[1];
    const float* target = (const float*)d_in[2];
    float* out = (float*)d_out;

    unsigned* ctrl  = (unsigned*)d_ws;                       // 16 words
    float* meanarr  = (float*)(ctrl + 16);                   // 6*72
    float* plv      = meanarr + ITERS * H * AD;              // GCAP
    unsigned* pli   = (unsigned*)(plv + GCAP);               // GCAP
    float* lvb      = (float*)(pli + GCAP);                  // 6*GCAP
    unsigned* lib   = (unsigned*)(lvb + ITERS * GCAP);       // 6*GCAP

    k_zero<<<1, 64, 0, stream>>>(ctrl);
    for (int i = 0; i < ITERS; ++i)
        k_step<<<NWG, WGS, 0, stream>>>(pi, noise, target, ctrl, meanarr,
                                        plv, pli, lvb, lib, i);
    k_fin<<<1, 256, 0, stream>>>(pi, noise, ctrl, meanarr, plv, pli,
                                 lvb + (size_t)5 * GCAP, lib + (size_t)5 * GCAP, out);
}